// Round 5
// baseline (3197.864 us; speedup 1.0000x reference)
//
#include <hip/hip_runtime.h>
#include <hip/hip_bf16.h>
#include <math.h>

#define D_EMB  1024
#define T_TOK  1024
#define T1_TOK 768
#define T2_TOK 256
#define HMLP   4096
#define NLAYER 12
#define VCLS   512

typedef __attribute__((ext_vector_type(8))) short          short8; // 8 bf16
typedef __attribute__((ext_vector_type(4))) float          f32x4;
typedef __attribute__((ext_vector_type(4))) unsigned short us4;

__device__ __forceinline__ unsigned short f2bf(float f) {
    union { float f; unsigned int u; } c; c.f = f;
    unsigned int u = c.u;
    return (unsigned short)((u + 0x7FFFu + ((u >> 16) & 1u)) >> 16); // RNE
}

__device__ __forceinline__ void gld_lds16(const unsigned short* g, unsigned short* l) {
    __builtin_amdgcn_global_load_lds(
        (__attribute__((address_space(1))) void*)g,
        (__attribute__((address_space(3))) void*)l, 16, 0, 0);
}

// ---------------------------------------------------------------------------
__global__ __launch_bounds__(256)
void embed_kernel(const int* __restrict__ xt, const int* __restrict__ zi,
                  const float* __restrict__ pos, const float* __restrict__ temb,
                  const float* __restrict__ iemb, float* __restrict__ H)
{
    const long idx = (long)blockIdx.x * 256 + threadIdx.x;
    const long e   = idx * 4;
    const int  dd  = (int)(e & (D_EMB - 1));
    const long bt  = e >> 10;
    const int  t   = (int)(bt & (T_TOK - 1));
    const int  b   = (int)(bt >> 10);
    const float* src;
    if (t < T2_TOK) src = iemb + (long)zi[b * T2_TOK + t] * D_EMB + dd;
    else            src = temb + (long)xt[b * T1_TOK + (t - T2_TOK)] * D_EMB + dd;
    float4 sv = *(const float4*)src;
    float4 pv = *(const float4*)(pos + (long)t * D_EMB + dd);
    float4 o; o.x = sv.x + pv.x; o.y = sv.y + pv.y; o.z = sv.z + pv.z; o.w = sv.w + pv.w;
    *(float4*)(H + e) = o;
}

// ---------------------------------------------------------------------------
__global__ __launch_bounds__(256)
void ln_kernel(const float* __restrict__ X, const float* __restrict__ g,
               const float* __restrict__ b, unsigned short* __restrict__ Y)
{
    const long row = blockIdx.x;
    const int  tid = threadIdx.x;
    float4 v = *(const float4*)(X + row * D_EMB + tid * 4);
    float s = v.x + v.y + v.z + v.w;
    float q = v.x*v.x + v.y*v.y + v.z*v.z + v.w*v.w;
    #pragma unroll
    for (int o = 32; o >= 1; o >>= 1) { s += __shfl_down(s, o); q += __shfl_down(q, o); }
    __shared__ float rs[4], rq[4];
    const int w = tid >> 6;
    if ((tid & 63) == 0) { rs[w] = s; rq[w] = q; }
    __syncthreads();
    s = rs[0] + rs[1] + rs[2] + rs[3];
    q = rq[0] + rq[1] + rq[2] + rq[3];
    const float mean = s * (1.0f / D_EMB);
    const float var  = q * (1.0f / D_EMB) - mean * mean;
    const float rstd = rsqrtf(var + 1e-5f);
    float4 gg = *(const float4*)(g + tid * 4);
    float4 bb = *(const float4*)(b + tid * 4);
    us4 o;
    o.x = f2bf((v.x - mean) * rstd * gg.x + bb.x);
    o.y = f2bf((v.y - mean) * rstd * gg.y + bb.y);
    o.z = f2bf((v.z - mean) * rstd * gg.z + bb.z);
    o.w = f2bf((v.w - mean) * rstd * gg.w + bb.w);
    *(us4*)(Y + row * D_EMB + tid * 4) = o;
}

// ---------------------------------------------------------------------------
__global__ __launch_bounds__(256)
void softmax_kernel(const float* __restrict__ S, unsigned short* __restrict__ P)
{
    const long row = blockIdx.x;
    const int  tid = threadIdx.x;
    float4 v = *(const float4*)(S + row * T_TOK + tid * 4);
    const float sc = 0.03125f; // 1/sqrt(1024)
    float a = v.x * sc, b = v.y * sc, c = v.z * sc, d = v.w * sc;
    float mx = fmaxf(fmaxf(a, b), fmaxf(c, d));
    #pragma unroll
    for (int o = 32; o >= 1; o >>= 1) mx = fmaxf(mx, __shfl_down(mx, o));
    __shared__ float rm[4], rsum[4];
    const int w = tid >> 6;
    if ((tid & 63) == 0) rm[w] = mx;
    __syncthreads();
    mx = fmaxf(fmaxf(rm[0], rm[1]), fmaxf(rm[2], rm[3]));
    float e0 = expf(a - mx), e1 = expf(b - mx), e2 = expf(c - mx), e3 = expf(d - mx);
    float s = e0 + e1 + e2 + e3;
    #pragma unroll
    for (int o = 32; o >= 1; o >>= 1) s += __shfl_down(s, o);
    if ((tid & 63) == 0) rsum[w] = s;
    __syncthreads();
    s = rsum[0] + rsum[1] + rsum[2] + rsum[3];
    const float inv = 1.0f / s;
    us4 o4; o4.x = f2bf(e0 * inv); o4.y = f2bf(e1 * inv);
    o4.z = f2bf(e2 * inv); o4.w = f2bf(e3 * inv);
    *(us4*)(P + row * T_TOK + tid * 4) = o4;
}

// ---------------------------------------------------------------------------
__global__ __launch_bounds__(256)
void convT_kernel(const float* __restrict__ src, unsigned short* __restrict__ dst,
                  int K, int N)
{
    __shared__ unsigned short tile[32][33];
    const int tn = blockIdx.x, tk = blockIdx.y;
    const int tx = threadIdx.x & 31, ty = threadIdx.x >> 5;
    #pragma unroll
    for (int i = 0; i < 4; ++i) {
        const int r = ty + i * 8;
        tile[r][tx] = f2bf(src[(long)(tk * 32 + r) * N + tn * 32 + tx]);
    }
    __syncthreads();
    #pragma unroll
    for (int i = 0; i < 4; ++i) {
        const int r = ty + i * 8;
        dst[(long)(tn * 32 + r) * K + tk * 32 + tx] = tile[tx][r];
    }
}

// fp32 [K][N] -> bf16 [N][K], 64x64 tiles, float4 loads / us4 stores.
// grid.x = 768 (Wq,Wk,Wv) + 1024 (W1) + 1024 (W2) = 2816
__global__ __launch_bounds__(256)
void wconv_kernel(const float* __restrict__ Wq, const float* __restrict__ Wk,
                  const float* __restrict__ Wv, const float* __restrict__ W1,
                  const float* __restrict__ W2,
                  unsigned short* __restrict__ WqT, unsigned short* __restrict__ WkT,
                  unsigned short* __restrict__ WvT, unsigned short* __restrict__ W1T,
                  unsigned short* __restrict__ W2T)
{
    __shared__ unsigned short tile[64][66];
    const int t = blockIdx.x;
    const float* src; unsigned short* dst; int K, N, tk, tn;
    if (t < 768) {
        const int wsel = t >> 8, tt = t & 255;
        src = (wsel == 0) ? Wq : (wsel == 1) ? Wk : Wv;
        dst = (wsel == 0) ? WqT : (wsel == 1) ? WkT : WvT;
        K = 1024; N = 1024; tk = tt >> 4; tn = tt & 15;
    } else if (t < 1792) {
        const int tt = t - 768;
        src = W1; dst = W1T; K = 1024; N = 4096; tk = tt >> 6; tn = tt & 63;
    } else {
        const int tt = t - 1792;
        src = W2; dst = W2T; K = 4096; N = 1024; tk = tt >> 4; tn = tt & 15;
    }
    const int r  = threadIdx.x >> 4;   // 0..15
    const int c4 = threadIdx.x & 15;   // col group
    #pragma unroll
    for (int i = 0; i < 4; ++i) {
        const int row = r + i * 16;
        float4 v = *(const float4*)(src + (long)(tk * 64 + row) * N + tn * 64 + c4 * 4);
        tile[row][c4 * 4 + 0] = f2bf(v.x);
        tile[row][c4 * 4 + 1] = f2bf(v.y);
        tile[row][c4 * 4 + 2] = f2bf(v.z);
        tile[row][c4 * 4 + 3] = f2bf(v.w);
    }
    __syncthreads();
    #pragma unroll
    for (int i = 0; i < 4; ++i) {
        const int rr = r + i * 16;     // transposed row = original col
        us4 o;
        o.x = tile[c4 * 4 + 0][rr];
        o.y = tile[c4 * 4 + 1][rr];
        o.z = tile[c4 * 4 + 2][rr];
        o.w = tile[c4 * 4 + 3][rr];
        *(us4*)(dst + (long)(tn * 64 + rr) * K + tk * 64 + c4 * 4) = o;
    }
}

__global__ __launch_bounds__(256)
void cvt_bf16_kernel(const float* __restrict__ X, unsigned short* __restrict__ Y)
{
    const long i = ((long)blockIdx.x * 256 + threadIdx.x) * 4;
    float4 v = *(const float4*)(X + i);
    us4 o; o.x = f2bf(v.x); o.y = f2bf(v.y); o.z = f2bf(v.z); o.w = f2bf(v.w);
    *(us4*)(Y + i) = o;
}

// ---------------------------------------------------------------------------
// bf16 GEMM, 3-buffer 2-deep pipeline (T4 counted-vmcnt):
//   iter t: issue STAGE(t+2)->buf[(t+2)%3]; ds_read+MFMA on buf[t%3];
//   s_waitcnt vmcnt(LPT) (own t+1 loads landed, t+2's stay in flight);
//   raw s_barrier. vmcnt never drains to 0 in steady state.
// Safety: each wave waits its OWN loads; barrier then implies the whole
// buffer is written. Buffer reuse (t+2 overwrites t-1) is fenced by the
// previous barrier (all ds_reads of t-1 were consumed by MFMAs before it).
// C = epi(A @ B^T). A [M][K] bf16, B [N][K] bf16. Tile 128 x TN, BK=32,
// 4 waves (2x2). k-slot XOR swizzle on global source + ds_read (rule #21).
// EPI: 0 fp32 | 1 bias+gelu->bf16 | 3 C+=alpha*v | 4 readout (24-tile remap)
//      | 5 bf16 | 6 atomicAdd(v+bias@z0) | 7 QKV combo (bf16; z==2 -> V^T)
// ---------------------------------------------------------------------------
template<int EPI, int TN>
__global__ __launch_bounds__(256)
void gemm_bt(const unsigned short* __restrict__ A,
             const unsigned short* __restrict__ B0,
             const unsigned short* __restrict__ B1,
             const unsigned short* __restrict__ B2,
             void* __restrict__ C0, void* __restrict__ C1, void* __restrict__ C2,
             const float* __restrict__ bias,
             int M, int N, int K, int kLen,
             long sAz, long sBz, long sCz, float alpha)
{
    constexpr int FN = TN / 32;          // B frags per wave
    constexpr int ABUF = 128 * 32;       // us per A buffer
    constexpr int BBUF = TN * 32;
    __shared__ unsigned short As[3 * ABUF];
    __shared__ unsigned short Bs[3 * BBUF];

    const int z = blockIdx.z;
    const unsigned short* Ap = A + (long)z * sAz;
    const unsigned short* Bp = (B1 != nullptr) ? (z == 0 ? B0 : (z == 1 ? B1 : B2))
                                               : B0 + (long)z * sBz;
    void* Cp = (C1 != nullptr) ? (z == 0 ? C0 : (z == 1 ? C1 : C2)) : C0;
    const long czoff = (C1 != nullptr) ? 0 : (long)z * sCz;

    // XCD swizzle (bijective: all launches have gx*gy % 8 == 0)
    const int gx = gridDim.x, gy = gridDim.y;
    const int o  = blockIdx.x + gx * blockIdx.y;
    const int nwg = gx * gy;
    const int virt = (nwg & 7) ? o : ((o & 7) * (nwg >> 3) + (o >> 3));
    const int ntile = virt / gy;
    int mtile = virt - ntile * gy;
    if constexpr (EPI == 4) mtile = (mtile / 6) * 8 + 2 + (mtile % 6); // t>=T2 tiles only
    const int m0 = mtile * 128, n0 = ntile * TN;
    const int kOff = (kLen < K) ? z * kLen : 0;

    const int tid = threadIdx.x;
    const int l = tid & 63, w = tid >> 6;
    const int wm = (w >> 1) * 64, wn = (w & 1) * (TN / 2);
    const int lr = l & 15, hi = l >> 4;

    // staging: 4 lanes/row (16B each), swizzled global k-slot
    const int r0 = tid >> 2;
    const int s0 = (tid & 3) ^ ((r0 >> 1) & 3);
    const unsigned short* gA0 = Ap + (long)(m0 + r0) * K + kOff + s0 * 8;
    const unsigned short* gA1 = Ap + (long)(m0 + r0 + 64) * K + kOff + s0 * 8;
    const unsigned short* gB0 = Bp + (long)(n0 + r0) * K + kOff + s0 * 8;
    const unsigned short* gB1 = (TN == 128) ? Bp + (long)(n0 + r0 + 64) * K + kOff + s0 * 8
                                            : nullptr;
    const int lA0 = w * 512, lA1 = 2048 + w * 512;
    const int lB0 = w * 512, lB1 = 2048 + w * 512;

    f32x4 acc[4][FN];
    #pragma unroll
    for (int f = 0; f < 4; ++f)
        #pragma unroll
        for (int gq = 0; gq < FN; ++gq)
            acc[f][gq] = (f32x4){0.f, 0.f, 0.f, 0.f};

    const int nk = kLen >> 5;
    auto STAGE = [&](int t, int buf) {
        const int k = t << 5;
        gld_lds16(gA0 + k, As + buf * ABUF + lA0);
        gld_lds16(gA1 + k, As + buf * ABUF + lA1);
        gld_lds16(gB0 + k, Bs + buf * BBUF + lB0);
        if constexpr (TN == 128) gld_lds16(gB1 + k, Bs + buf * BBUF + lB1);
    };

    // prologue: tiles 0 and 1 in flight; wait tile 0 only
    STAGE(0, 0);
    if (nk > 1) {
        STAGE(1, 1);
        if constexpr (TN == 128) asm volatile("s_waitcnt vmcnt(4)" ::: "memory");
        else                     asm volatile("s_waitcnt vmcnt(3)" ::: "memory");
    } else {
        asm volatile("s_waitcnt vmcnt(0)" ::: "memory");
    }
    __builtin_amdgcn_s_barrier();
    __builtin_amdgcn_sched_barrier(0);

    for (int t = 0; t < nk; ++t) {
        const int cur = t % 3;
        if (t + 2 < nk) STAGE(t + 2, (t + 2) % 3);
        const int aC = cur * ABUF, bC = cur * BBUF;
        short8 af[4], bg[FN];
        #pragma unroll
        for (int f = 0; f < 4; ++f) {
            const int rr = wm + f * 16 + lr;
            const int sl = hi ^ ((rr >> 1) & 3);
            af[f] = *(const short8*)&As[aC + rr * 32 + sl * 8];
        }
        #pragma unroll
        for (int gq = 0; gq < FN; ++gq) {
            const int rn = wn + gq * 16 + lr;
            const int sl = hi ^ ((rn >> 1) & 3);
            bg[gq] = *(const short8*)&Bs[bC + rn * 32 + sl * 8];
        }
        #pragma unroll
        for (int f = 0; f < 4; ++f)
            #pragma unroll
            for (int gq = 0; gq < FN; ++gq)
                acc[f][gq] = __builtin_amdgcn_mfma_f32_16x16x32_bf16(
                    af[f], bg[gq], acc[f][gq], 0, 0, 0);
        __builtin_amdgcn_sched_barrier(0);
        if (t + 2 < nk) {       // t+1's loads done; t+2's (LPT) stay in flight
            if constexpr (TN == 128) asm volatile("s_waitcnt vmcnt(4)" ::: "memory");
            else                     asm volatile("s_waitcnt vmcnt(3)" ::: "memory");
        } else if (t + 1 < nk) { // nothing issued this iter; drain t+1
            asm volatile("s_waitcnt vmcnt(0)" ::: "memory");
        }
        __builtin_amdgcn_s_barrier();
        __builtin_amdgcn_sched_barrier(0);
    }

    // D mapping: col = lane&15, row = (lane>>4)*4 + r
    #pragma unroll
    for (int f = 0; f < 4; ++f) {
        #pragma unroll
        for (int gq = 0; gq < FN; ++gq) {
            const int gm0 = m0 + wm + f * 16 + hi * 4;
            const int gn  = n0 + wn + gq * 16 + lr;
            if constexpr (EPI == 7) {
                if (z == 2) { // V^T: VT[b][d=gn][t], 4 consecutive t
                    us4 ov;
                    ov.x = f2bf(acc[f][gq][0]); ov.y = f2bf(acc[f][gq][1]);
                    ov.z = f2bf(acc[f][gq][2]); ov.w = f2bf(acc[f][gq][3]);
                    const long idx = (long)(gm0 >> 10) * (T_TOK * D_EMB)
                                   + (long)gn * T_TOK + (gm0 & (T_TOK - 1));
                    *(us4*)&((unsigned short*)Cp)[idx] = ov;
                    continue;
                }
            }
            #pragma unroll
            for (int r = 0; r < 4; ++r) {
                const int gm = gm0 + r;
                float v = acc[f][gq][r];
                if constexpr (EPI == 0) {
                    ((float*)Cp)[czoff + (long)gm * N + gn] = v;
                } else if constexpr (EPI == 1) {
                    v += bias[gn];
                    const float ge = 0.5f * v * (1.0f + erff(v * 0.70710678118f));
                    ((unsigned short*)Cp)[(long)gm * N + gn] = f2bf(ge);
                } else if constexpr (EPI == 3) {
                    float* c = (float*)Cp + czoff + (long)gm * N + gn;
                    *c = *c + alpha * v;
                } else if constexpr (EPI == 4) {
                    const int tt = gm & (T_TOK - 1);
                    ((float*)Cp)[(long)((gm >> 10) * T1_TOK + (tt - T2_TOK)) * VCLS + gn]
                        = v + bias[gn];
                } else if constexpr (EPI == 5 || EPI == 7) {
                    ((unsigned short*)Cp)[(long)gm * N + gn] = f2bf(v);
                } else if constexpr (EPI == 6) {
                    atomicAdd((float*)Cp + (long)gm * N + gn,
                              v + ((z == 0) ? bias[gn] : 0.f));
                }
            }
        }
    }
}

// ---------------------------------------------------------------------------
extern "C" void kernel_launch(void* const* d_in, const int* in_sizes, int n_in,
                              void* d_out, int out_size, void* d_ws, size_t ws_size,
                              hipStream_t stream)
{
    (void)in_sizes; (void)n_in; (void)out_size; (void)ws_size;
    const int*   xt   = (const int*)d_in[0];
    const int*   zi   = (const int*)d_in[1];
    const float* pos  = (const float*)d_in[2];
    const float* temb = (const float*)d_in[3];
    const float* iemb = (const float*)d_in[4];
    const float* ln1g = (const float*)d_in[5];
    const float* ln1b = (const float*)d_in[6];
    const float* Wq   = (const float*)d_in[7];
    const float* Wk   = (const float*)d_in[8];
    const float* Wv   = (const float*)d_in[9];
    const float* ln2g = (const float*)d_in[10];
    const float* ln2b = (const float*)d_in[11];
    const float* W1   = (const float*)d_in[12];
    const float* b1   = (const float*)d_in[13];
    const float* W2   = (const float*)d_in[14];
    const float* b2   = (const float*)d_in[15];
    const float* roW  = (const float*)d_in[16];
    const float* rob  = (const float*)d_in[17];
    float* out = (float*)d_out;

    char* wsb = (char*)d_ws;
    float*          H    = (float*)(wsb + 0);                 // 16 MB fp32
    unsigned short* LNb  = (unsigned short*)(wsb + 16777216); // 8 MB bf16
    float*          S    = (float*)(wsb + 25165824);          // 16 MB fp32
    unsigned short* Qb   = (unsigned short*)(wsb + 41943040); // 8 MB
    unsigned short* Kb   = (unsigned short*)(wsb + 50331648); // 8 MB
    unsigned short* VT   = (unsigned short*)(wsb + 58720256); // 8 MB (V^T per batch)
    unsigned short* Pb   = (unsigned short*)(wsb + 67108864); // 8 MB
    unsigned short* Hid  = (unsigned short*)(wsb + 41943040); // 32 MB, overlaps Q..P
    unsigned short* WqT  = (unsigned short*)(wsb + 75497472); // 2 MB
    unsigned short* WkT  = (unsigned short*)(wsb + 77594624);
    unsigned short* WvT  = (unsigned short*)(wsb + 79691776);
    unsigned short* W1T  = (unsigned short*)(wsb + 81788928); // 8 MB
    unsigned short* W2T  = (unsigned short*)(wsb + 90177536); // 8 MB
    unsigned short* roWT = W1T;
    unsigned short* Hbf  = LNb;

    const long TD = (long)T_TOK * D_EMB;
    const long TT = (long)T_TOK * T_TOK;

    embed_kernel<<<4096, 256, 0, stream>>>(xt, zi, pos, temb, iemb, H);

    for (int lyr = 0; lyr < NLAYER; ++lyr) {
        const long dd = (long)lyr * D_EMB * D_EMB;
        const long d1 = (long)lyr * D_EMB * HMLP;
        wconv_kernel<<<2816, 256, 0, stream>>>(
            Wq + dd, Wk + dd, Wv + dd, W1 + d1, W2 + d1,
            WqT, WkT, WvT, W1T, W2T);
        ln_kernel<<<4096, 256, 0, stream>>>(H, ln1g + lyr * D_EMB, ln1b + lyr * D_EMB, LNb);
        // Q,K,V projections; z==2 writes V^T directly
        gemm_bt<7, 128><<<dim3(8, 32, 3), 256, 0, stream>>>(
            LNb, WqT, WkT, WvT, Qb, Kb, VT, nullptr,
            4096, D_EMB, D_EMB, D_EMB, 0L, 0L, 0L, 1.f);
        // scores = Q @ K^T per batch
        gemm_bt<0, 64><<<dim3(16, 8, 4), 256, 0, stream>>>(
            Qb, Kb, nullptr, nullptr, S, nullptr, nullptr, nullptr,
            T_TOK, T_TOK, D_EMB, D_EMB, TD, TD, TT, 1.f);
        softmax_kernel<<<4096, 256, 0, stream>>>(S, Pb);
        // H += (1 + 1/D) * P @ V
        gemm_bt<3, 64><<<dim3(16, 8, 4), 256, 0, stream>>>(
            Pb, VT, nullptr, nullptr, H, nullptr, nullptr, nullptr,
            T_TOK, D_EMB, T_TOK, T_TOK, TT, TD, TD, 1.0f + 1.0f / (float)D_EMB);
        ln_kernel<<<4096, 256, 0, stream>>>(H, ln2g + lyr * D_EMB, ln2b + lyr * D_EMB, LNb);
        // hidden = gelu(LN @ W1 + b1) -> bf16
        gemm_bt<1, 128><<<dim3(32, 32, 1), 256, 0, stream>>>(
            LNb, W1T, nullptr, nullptr, Hid, nullptr, nullptr, b1 + (long)lyr * HMLP,
            4096, HMLP, D_EMB, D_EMB, 0L, 0L, 0L, 1.f);
        // H += hidden @ W2 + b2  (split-K x2, atomic accumulate)
        gemm_bt<6, 128><<<dim3(8, 32, 2), 256, 0, stream>>>(
            Hid, W2T, nullptr, nullptr, H, nullptr, nullptr, b2 + (long)lyr * D_EMB,
            4096, D_EMB, HMLP, HMLP / 2, 0L, 0L, 0L, 1.f);
    }
    // readout: out = (H @ ro_W + ro_b)[:, T2:, :]  (only the 24 needed m-tiles)
    cvt_bf16_kernel<<<4096, 256, 0, stream>>>(H, Hbf);
    convT_kernel<<<dim3(16, 32), 256, 0, stream>>>(roW, roWT, D_EMB, VCLS);
    gemm_bt<4, 64><<<dim3(8, 24, 1), 256, 0, stream>>>(
        Hbf, roWT, nullptr, nullptr, out, nullptr, nullptr, rob,
        4096, VCLS, D_EMB, D_EMB, 0L, 0L, 0L, 1.f);
}

// Round 6
// 3052.519 us; speedup vs baseline: 1.0476x; 1.0476x over previous
//
#include <hip/hip_runtime.h>
#include <hip/hip_bf16.h>
#include <math.h>

#define D_EMB  1024
#define T_TOK  1024
#define T1_TOK 768
#define T2_TOK 256
#define HMLP   4096
#define NLAYER 12
#define VCLS   512

typedef __attribute__((ext_vector_type(8))) short          short8; // 8 bf16
typedef __attribute__((ext_vector_type(4))) float          f32x4;
typedef __attribute__((ext_vector_type(4))) unsigned short us4;
typedef unsigned short us;

__device__ __forceinline__ us f2bf(float f) {
    union { float f; unsigned int u; } c; c.f = f;
    unsigned int u = c.u;
    return (us)((u + 0x7FFFu + ((u >> 16) & 1u)) >> 16); // RNE
}

__device__ __forceinline__ void gld_lds16(const us* g, us* l) {
    __builtin_amdgcn_global_load_lds(
        (__attribute__((address_space(1))) void*)g,
        (__attribute__((address_space(3))) void*)l, 16, 0, 0);
}

// ---------------------------------------------------------------------------
__global__ __launch_bounds__(256)
void embed_kernel(const int* __restrict__ xt, const int* __restrict__ zi,
                  const float* __restrict__ pos, const float* __restrict__ temb,
                  const float* __restrict__ iemb, float* __restrict__ H)
{
    const long idx = (long)blockIdx.x * 256 + threadIdx.x;
    const long e   = idx * 4;
    const int  dd  = (int)(e & (D_EMB - 1));
    const long bt  = e >> 10;
    const int  t   = (int)(bt & (T_TOK - 1));
    const int  b   = (int)(bt >> 10);
    const float* src;
    if (t < T2_TOK) src = iemb + (long)zi[b * T2_TOK + t] * D_EMB + dd;
    else            src = temb + (long)xt[b * T1_TOK + (t - T2_TOK)] * D_EMB + dd;
    float4 sv = *(const float4*)src;
    float4 pv = *(const float4*)(pos + (long)t * D_EMB + dd);
    float4 o; o.x = sv.x + pv.x; o.y = sv.y + pv.y; o.z = sv.z + pv.z; o.w = sv.w + pv.w;
    *(float4*)(H + e) = o;
}

// ---------------------------------------------------------------------------
__global__ __launch_bounds__(256)
void ln_kernel(const float* __restrict__ X, const float* __restrict__ g,
               const float* __restrict__ b, us* __restrict__ Y)
{
    const long row = blockIdx.x;
    const int  tid = threadIdx.x;
    float4 v = *(const float4*)(X + row * D_EMB + tid * 4);
    float s = v.x + v.y + v.z + v.w;
    float q = v.x*v.x + v.y*v.y + v.z*v.z + v.w*v.w;
    #pragma unroll
    for (int o = 32; o >= 1; o >>= 1) { s += __shfl_down(s, o); q += __shfl_down(q, o); }
    __shared__ float rs[4], rq[4];
    const int w = tid >> 6;
    if ((tid & 63) == 0) { rs[w] = s; rq[w] = q; }
    __syncthreads();
    s = rs[0] + rs[1] + rs[2] + rs[3];
    q = rq[0] + rq[1] + rq[2] + rq[3];
    const float mean = s * (1.0f / D_EMB);
    const float var  = q * (1.0f / D_EMB) - mean * mean;
    const float rstd = rsqrtf(var + 1e-5f);
    float4 gg = *(const float4*)(g + tid * 4);
    float4 bb = *(const float4*)(b + tid * 4);
    us4 o;
    o.x = f2bf((v.x - mean) * rstd * gg.x + bb.x);
    o.y = f2bf((v.y - mean) * rstd * gg.y + bb.y);
    o.z = f2bf((v.z - mean) * rstd * gg.z + bb.z);
    o.w = f2bf((v.w - mean) * rstd * gg.w + bb.w);
    *(us4*)(Y + row * D_EMB + tid * 4) = o;
}

// ---------------------------------------------------------------------------
__global__ __launch_bounds__(256)
void softmax_kernel(const float* __restrict__ S, us* __restrict__ P)
{
    const long row = blockIdx.x;
    const int  tid = threadIdx.x;
    float4 v = *(const float4*)(S + row * T_TOK + tid * 4);
    const float sc = 0.03125f; // 1/sqrt(1024)
    float a = v.x * sc, b = v.y * sc, c = v.z * sc, d = v.w * sc;
    float mx = fmaxf(fmaxf(a, b), fmaxf(c, d));
    #pragma unroll
    for (int o = 32; o >= 1; o >>= 1) mx = fmaxf(mx, __shfl_down(mx, o));
    __shared__ float rm[4], rsum[4];
    const int w = tid >> 6;
    if ((tid & 63) == 0) rm[w] = mx;
    __syncthreads();
    mx = fmaxf(fmaxf(rm[0], rm[1]), fmaxf(rm[2], rm[3]));
    float e0 = expf(a - mx), e1 = expf(b - mx), e2 = expf(c - mx), e3 = expf(d - mx);
    float s = e0 + e1 + e2 + e3;
    #pragma unroll
    for (int o = 32; o >= 1; o >>= 1) s += __shfl_down(s, o);
    if ((tid & 63) == 0) rsum[w] = s;
    __syncthreads();
    s = rsum[0] + rsum[1] + rsum[2] + rsum[3];
    const float inv = 1.0f / s;
    us4 o4; o4.x = f2bf(e0 * inv); o4.y = f2bf(e1 * inv);
    o4.z = f2bf(e2 * inv); o4.w = f2bf(e3 * inv);
    *(us4*)(P + row * T_TOK + tid * 4) = o4;
}

// ---------------------------------------------------------------------------
__global__ __launch_bounds__(256)
void convT_kernel(const float* __restrict__ src, us* __restrict__ dst,
                  int K, int N)
{
    __shared__ us tile[32][33];
    const int tn = blockIdx.x, tk = blockIdx.y;
    const int tx = threadIdx.x & 31, ty = threadIdx.x >> 5;
    #pragma unroll
    for (int i = 0; i < 4; ++i) {
        const int r = ty + i * 8;
        tile[r][tx] = f2bf(src[(long)(tk * 32 + r) * N + tn * 32 + tx]);
    }
    __syncthreads();
    #pragma unroll
    for (int i = 0; i < 4; ++i) {
        const int r = ty + i * 8;
        dst[(long)(tn * 32 + r) * K + tk * 32 + tx] = tile[tx][r];
    }
}

// fp32 [K][N] -> bf16 [N][K], 64x64 tiles (float4 in / us4 out)
__global__ __launch_bounds__(256)
void wconv_kernel(const float* __restrict__ Wq, const float* __restrict__ Wk,
                  const float* __restrict__ Wv, const float* __restrict__ W1,
                  const float* __restrict__ W2,
                  us* __restrict__ WqT, us* __restrict__ WkT,
                  us* __restrict__ WvT, us* __restrict__ W1T,
                  us* __restrict__ W2T)
{
    __shared__ us tile[64][66];
    const int t = blockIdx.x;
    const float* src; us* dst; int K, N, tk, tn;
    if (t < 768) {
        const int wsel = t >> 8, tt = t & 255;
        src = (wsel == 0) ? Wq : (wsel == 1) ? Wk : Wv;
        dst = (wsel == 0) ? WqT : (wsel == 1) ? WkT : WvT;
        K = 1024; N = 1024; tk = tt >> 4; tn = tt & 15;
    } else if (t < 1792) {
        const int tt = t - 768;
        src = W1; dst = W1T; K = 1024; N = 4096; tk = tt >> 6; tn = tt & 63;
    } else {
        const int tt = t - 1792;
        src = W2; dst = W2T; K = 4096; N = 1024; tk = tt >> 4; tn = tt & 15;
    }
    const int r  = threadIdx.x >> 4;
    const int c4 = threadIdx.x & 15;
    #pragma unroll
    for (int i = 0; i < 4; ++i) {
        const int row = r + i * 16;
        float4 v = *(const float4*)(src + (long)(tk * 64 + row) * N + tn * 64 + c4 * 4);
        tile[row][c4 * 4 + 0] = f2bf(v.x);
        tile[row][c4 * 4 + 1] = f2bf(v.y);
        tile[row][c4 * 4 + 2] = f2bf(v.z);
        tile[row][c4 * 4 + 3] = f2bf(v.w);
    }
    __syncthreads();
    #pragma unroll
    for (int i = 0; i < 4; ++i) {
        const int rr = r + i * 16;
        us4 o;
        o.x = tile[c4 * 4 + 0][rr];
        o.y = tile[c4 * 4 + 1][rr];
        o.z = tile[c4 * 4 + 2][rr];
        o.w = tile[c4 * 4 + 3][rr];
        *(us4*)(dst + (long)(tn * 64 + rr) * K + tk * 64 + c4 * 4) = o;
    }
}

__global__ __launch_bounds__(256)
void cvt_bf16_kernel(const float* __restrict__ X, us* __restrict__ Y)
{
    const long i = ((long)blockIdx.x * 256 + threadIdx.x) * 4;
    float4 v = *(const float4*)(X + i);
    us4 o; o.x = f2bf(v.x); o.y = f2bf(v.y); o.z = f2bf(v.z); o.w = f2bf(v.w);
    *(us4*)(Y + i) = o;
}

// ===========================================================================
// gemm8: 256x128 tile, BK=64, 8 waves (4Mx2N), 512 thr, triple-buffered LDS
// (144 KB, 1 block/CU), 2 phases/K-tile:
//   { 8x ds_read_b128 | 3x gld_lds prefetch(t+2) -> s_barrier ->
//     lgkmcnt(0) -> setprio(1) 16x MFMA setprio(0) -> [vmcnt(6)] s_barrier }
// vmcnt(6) once per K-tile: own t+1 loads landed, t+2's 6 stay in flight.
// Swizzle (BK=64): LDS slot' = slot ^ (row&7); linear gld_lds dest +
// pre-swizzled global source + swizzled ds_read (rule #21).
// EPI: 1 bias+gelu->bf16 | 6 atomicAdd(v+bias@z0), split-K via z |
//      7 QKV fused over N=3072 (n>>10: 0->Q bf16, 1->K bf16, 2->V^T us4)
// ===========================================================================
template<int EPI>
__global__ __launch_bounds__(512, 2)
void gemm8(const us* __restrict__ A, const us* __restrict__ B,
           void* __restrict__ C0, void* __restrict__ C1, void* __restrict__ C2,
           const float* __restrict__ bias,
           int N, int K, int kLen)
{
    constexpr int ABUF = 256 * 64;   // us per A buffer (32 KB)
    constexpr int BBUF = 128 * 64;   // us per B buffer (16 KB)
    __shared__ us As[3 * ABUF];
    __shared__ us Bs[3 * BBUF];

    const int z = blockIdx.z;
    const int kOff = (kLen < K) ? z * kLen : 0;

    // XCD swizzle (bijective: nwg % 8 == 0 for all launches), n-major decode
    const int gx = gridDim.x, gy = gridDim.y;
    const int o  = blockIdx.x + gx * blockIdx.y;
    const int nwg = gx * gy;
    const int virt = (nwg & 7) ? o : ((o & 7) * (nwg >> 3) + (o >> 3));
    const int ntile = virt / gy;
    const int mtile = virt - ntile * gy;
    const int m0 = mtile * 256, n0 = ntile * 128;

    const int tid  = threadIdx.x;
    const int lane = tid & 63, w = tid >> 6;          // 8 waves
    const int srow = lane >> 3, sslot = (lane & 7) ^ srow;
    const int lr = lane & 15, hi = lane >> 4;
    const int wm = (w >> 1) * 64, wn = (w & 1) * 64;

    // staging bases: wave w stages A rows [w*32,+32), B rows [w*16,+16)
    const us* gA = A + (long)(m0 + w * 32 + srow) * K + kOff + sslot * 8;
    const us* gB = B + (long)(n0 + w * 16 + srow) * K + kOff + sslot * 8;

    f32x4 acc[4][4];
    #pragma unroll
    for (int f = 0; f < 4; ++f)
        #pragma unroll
        for (int g = 0; g < 4; ++g)
            acc[f][g] = (f32x4){0.f, 0.f, 0.f, 0.f};

    const int nk = kLen >> 6;  // K-tiles of 64 (>=16 for all our launches)

    // prologue: stage tiles 0,1; wait tile 0 (6 newest stay in flight)
    #pragma unroll
    for (int j = 0; j < 4; ++j)
        gld_lds16(gA + (long)(j * 8) * K + 0, As + 0 * ABUF + (w * 32 + j * 8) * 64);
    #pragma unroll
    for (int j = 0; j < 2; ++j)
        gld_lds16(gB + (long)(j * 8) * K + 0, Bs + 0 * BBUF + (w * 16 + j * 8) * 64);
    #pragma unroll
    for (int j = 0; j < 4; ++j)
        gld_lds16(gA + (long)(j * 8) * K + 64, As + 1 * ABUF + (w * 32 + j * 8) * 64);
    #pragma unroll
    for (int j = 0; j < 2; ++j)
        gld_lds16(gB + (long)(j * 8) * K + 64, Bs + 1 * BBUF + (w * 16 + j * 8) * 64);
    asm volatile("s_waitcnt vmcnt(6)" ::: "memory");
    __builtin_amdgcn_s_barrier();

    for (int t = 0; t < nk; ++t) {
        const int cur = t % 3, nb = (t + 2) % 3;
        const us* Ac = As + cur * ABUF;
        const us* Bc = Bs + cur * BBUF;
        const int kk2 = (t + 2) << 6;
        #pragma unroll
        for (int kk = 0; kk < 2; ++kk) {
            short8 af[4], bg[4];
            #pragma unroll
            for (int f = 0; f < 4; ++f) {
                const int rr = wm + f * 16 + lr;
                af[f] = *(const short8*)&Ac[rr * 64 + (((kk * 4 + hi) ^ (rr & 7)) * 8)];
            }
            #pragma unroll
            for (int g = 0; g < 4; ++g) {
                const int rn = wn + g * 16 + lr;
                bg[g] = *(const short8*)&Bc[rn * 64 + (((kk * 4 + hi) ^ (rn & 7)) * 8)];
            }
            if (t + 2 < nk) {  // stage half kk of tile t+2 (3 gld_lds)
                gld_lds16(gA + (long)((kk * 2 + 0) * 8) * K + kk2,
                          As + nb * ABUF + (w * 32 + (kk * 2 + 0) * 8) * 64);
                gld_lds16(gA + (long)((kk * 2 + 1) * 8) * K + kk2,
                          As + nb * ABUF + (w * 32 + (kk * 2 + 1) * 8) * 64);
                gld_lds16(gB + (long)(kk * 8) * K + kk2,
                          Bs + nb * BBUF + (w * 16 + kk * 8) * 64);
            }
            __builtin_amdgcn_s_barrier();
            asm volatile("s_waitcnt lgkmcnt(0)" ::: "memory");
            __builtin_amdgcn_sched_barrier(0);
            __builtin_amdgcn_s_setprio(1);
            #pragma unroll
            for (int f = 0; f < 4; ++f)
                #pragma unroll
                for (int g = 0; g < 4; ++g)
                    acc[f][g] = __builtin_amdgcn_mfma_f32_16x16x32_bf16(
                        af[f], bg[g], acc[f][g], 0, 0, 0);
            __builtin_amdgcn_s_setprio(0);
            __builtin_amdgcn_sched_barrier(0);
            if (kk == 1) {
                if (t + 2 < nk)      asm volatile("s_waitcnt vmcnt(6)" ::: "memory");
                else if (t + 1 < nk) asm volatile("s_waitcnt vmcnt(0)" ::: "memory");
            }
            __builtin_amdgcn_s_barrier();
        }
    }

    // epilogue. D: col = lane&15 (n), row = hi*4 + r (m)
    #pragma unroll
    for (int f = 0; f < 4; ++f) {
        #pragma unroll
        for (int g = 0; g < 4; ++g) {
            const int gm0 = m0 + wm + f * 16 + hi * 4;
            const int gn  = n0 + wn + g * 16 + lr;
            if constexpr (EPI == 7) {
                const int target = gn >> 10, col = gn & 1023;
                if (target == 2) {  // V^T: VT[b][d][t], 4 consecutive t
                    us4 ov;
                    ov.x = f2bf(acc[f][g][0]); ov.y = f2bf(acc[f][g][1]);
                    ov.z = f2bf(acc[f][g][2]); ov.w = f2bf(acc[f][g][3]);
                    *(us4*)&((us*)C2)[(long)(gm0 >> 10) * (T_TOK * D_EMB)
                                      + (long)col * T_TOK + (gm0 & (T_TOK - 1))] = ov;
                } else {
                    us* dst = target ? (us*)C1 : (us*)C0;
                    #pragma unroll
                    for (int r = 0; r < 4; ++r)
                        dst[(long)(gm0 + r) * D_EMB + col] = f2bf(acc[f][g][r]);
                }
            } else if constexpr (EPI == 1) {
                #pragma unroll
                for (int r = 0; r < 4; ++r) {
                    float v = acc[f][g][r] + bias[gn];
                    const float ge = 0.5f * v * (1.0f + erff(v * 0.70710678118f));
                    ((us*)C0)[(long)(gm0 + r) * N + gn] = f2bf(ge);
                }
            } else { // EPI == 6
                #pragma unroll
                for (int r = 0; r < 4; ++r)
                    atomicAdd((float*)C0 + (long)(gm0 + r) * N + gn,
                              acc[f][g][r] + ((z == 0) ? bias[gn] : 0.f));
            }
        }
    }
}

// ---------------------------------------------------------------------------
// r4-proven 128xTN 2-buffer GEMM for QK / PV / readout.
// EPI: 0 fp32 | 3 C+=alpha*v | 4 readout slice
// ---------------------------------------------------------------------------
template<int EPI, int TN>
__global__ __launch_bounds__(256)
void gemm_bt(const us* __restrict__ A, const us* __restrict__ B0,
             void* __restrict__ C0, const float* __restrict__ bias,
             int M, int N, int K,
             long sAz, long sBz, long sCz, float alpha)
{
    constexpr int FN = TN / 32;
    constexpr int ABUF = 128 * 32;
    constexpr int BBUF = TN * 32;
    __shared__ us As[2 * ABUF];
    __shared__ us Bs[2 * BBUF];

    const int z = blockIdx.z;
    const us* Ap = A + (long)z * sAz;
    const us* Bp = B0 + (long)z * sBz;
    const long czoff = (long)z * sCz;

    const int gx = gridDim.x, gy = gridDim.y;
    const int o  = blockIdx.x + gx * blockIdx.y;
    const int nwg = gx * gy;
    const int virt = (nwg & 7) ? o : ((o & 7) * (nwg >> 3) + (o >> 3));
    const int ntile = virt / gy;
    int mtile = virt - ntile * gy;
    if constexpr (EPI == 4) mtile = (mtile / 6) * 8 + 2 + (mtile % 6);
    const int m0 = mtile * 128, n0 = ntile * TN;

    const int tid = threadIdx.x;
    const int l = tid & 63, w = tid >> 6;
    const int wm = (w >> 1) * 64, wn = (w & 1) * (TN / 2);
    const int lr = l & 15, hi = l >> 4;

    const int r0 = tid >> 2;
    const int s0 = (tid & 3) ^ ((r0 >> 1) & 3);
    const us* gA0 = Ap + (long)(m0 + r0) * K + s0 * 8;
    const us* gA1 = Ap + (long)(m0 + r0 + 64) * K + s0 * 8;
    const us* gB0 = Bp + (long)(n0 + r0) * K + s0 * 8;
    const us* gB1 = (TN == 128) ? Bp + (long)(n0 + r0 + 64) * K + s0 * 8 : nullptr;
    const int lA0 = w * 512, lA1 = 2048 + w * 512;
    const int lB0 = w * 512, lB1 = 2048 + w * 512;

    f32x4 acc[4][FN];
    #pragma unroll
    for (int f = 0; f < 4; ++f)
        #pragma unroll
        for (int gq = 0; gq < FN; ++gq)
            acc[f][gq] = (f32x4){0.f, 0.f, 0.f, 0.f};

    const int nk = K >> 5;
    gld_lds16(gA0, As + lA0);
    gld_lds16(gA1, As + lA1);
    gld_lds16(gB0, Bs + lB0);
    if constexpr (TN == 128) gld_lds16(gB1, Bs + lB1);
    __syncthreads();

    for (int t = 0; t < nk; ++t) {
        const int cur = t & 1;
        const int aB = (cur ^ 1) * ABUF, bB = (cur ^ 1) * BBUF;
        if (t + 1 < nk) {
            const int k1 = (t + 1) << 5;
            gld_lds16(gA0 + k1, As + aB + lA0);
            gld_lds16(gA1 + k1, As + aB + lA1);
            gld_lds16(gB0 + k1, Bs + bB + lB0);
            if constexpr (TN == 128) gld_lds16(gB1 + k1, Bs + bB + lB1);
        }
        const int aC = cur * ABUF, bC = cur * BBUF;
        short8 af[4], bg[FN];
        #pragma unroll
        for (int f = 0; f < 4; ++f) {
            const int rr = wm + f * 16 + lr;
            const int sl = hi ^ ((rr >> 1) & 3);
            af[f] = *(const short8*)&As[aC + rr * 32 + sl * 8];
        }
        #pragma unroll
        for (int gq = 0; gq < FN; ++gq) {
            const int rn = wn + gq * 16 + lr;
            const int sl = hi ^ ((rn >> 1) & 3);
            bg[gq] = *(const short8*)&Bs[bC + rn * 32 + sl * 8];
        }
        #pragma unroll
        for (int f = 0; f < 4; ++f)
            #pragma unroll
            for (int gq = 0; gq < FN; ++gq)
                acc[f][gq] = __builtin_amdgcn_mfma_f32_16x16x32_bf16(
                    af[f], bg[gq], acc[f][gq], 0, 0, 0);
        __syncthreads();
    }

    #pragma unroll
    for (int f = 0; f < 4; ++f) {
        #pragma unroll
        for (int gq = 0; gq < FN; ++gq) {
            #pragma unroll
            for (int r = 0; r < 4; ++r) {
                const int gm = m0 + wm + f * 16 + hi * 4 + r;
                const int gn = n0 + wn + gq * 16 + lr;
                float v = acc[f][gq][r];
                if constexpr (EPI == 0) {
                    ((float*)C0)[czoff + (long)gm * N + gn] = v;
                } else if constexpr (EPI == 3) {
                    float* c = (float*)C0 + czoff + (long)gm * N + gn;
                    *c = *c + alpha * v;
                } else { // EPI == 4
                    const int tt = gm & (T_TOK - 1);
                    ((float*)C0)[(long)((gm >> 10) * T1_TOK + (tt - T2_TOK)) * VCLS + gn]
                        = v + bias[gn];
                }
            }
        }
    }
}

// ---------------------------------------------------------------------------
extern "C" void kernel_launch(void* const* d_in, const int* in_sizes, int n_in,
                              void* d_out, int out_size, void* d_ws, size_t ws_size,
                              hipStream_t stream)
{
    (void)in_sizes; (void)n_in; (void)out_size; (void)ws_size;
    const int*   xt   = (const int*)d_in[0];
    const int*   zi   = (const int*)d_in[1];
    const float* pos  = (const float*)d_in[2];
    const float* temb = (const float*)d_in[3];
    const float* iemb = (const float*)d_in[4];
    const float* ln1g = (const float*)d_in[5];
    const float* ln1b = (const float*)d_in[6];
    const float* Wq   = (const float*)d_in[7];
    const float* Wk   = (const float*)d_in[8];
    const float* Wv   = (const float*)d_in[9];
    const float* ln2g = (const float*)d_in[10];
    const float* ln2b = (const float*)d_in[11];
    const float* W1   = (const float*)d_in[12];
    const float* b1   = (const float*)d_in[13];
    const float* W2   = (const float*)d_in[14];
    const float* b2   = (const float*)d_in[15];
    const float* roW  = (const float*)d_in[16];
    const float* rob  = (const float*)d_in[17];
    float* out = (float*)d_out;

    char* wsb = (char*)d_ws;
    float* H    = (float*)(wsb + 0);                 // 16 MB fp32
    us*    LNb  = (us*)(wsb + 16777216);             // 8 MB bf16
    float* S    = (float*)(wsb + 25165824);          // 16 MB fp32
    us*    Qb   = (us*)(wsb + 41943040);             // 8 MB
    us*    Kb   = (us*)(wsb + 50331648);             // 8 MB
    us*    VT   = (us*)(wsb + 58720256);             // 8 MB (V^T per batch)
    us*    Pb   = (us*)(wsb + 67108864);             // 8 MB
    us*    Hid  = (us*)(wsb + 41943040);             // 32 MB, overlaps Q..P
    us*    WqT  = (us*)(wsb + 75497472);             // 2 MB (Wq,Wk,Wv contiguous!)
    us*    WkT  = (us*)(wsb + 77594624);
    us*    WvT  = (us*)(wsb + 79691776);
    us*    W1T  = (us*)(wsb + 81788928);             // 8 MB
    us*    W2T  = (us*)(wsb + 90177536);             // 8 MB
    us*    roWT = W1T;
    us*    Hbf  = LNb;

    const long TD = (long)T_TOK * D_EMB;
    const long TT = (long)T_TOK * T_TOK;

    embed_kernel<<<4096, 256, 0, stream>>>(xt, zi, pos, temb, iemb, H);

    for (int lyr = 0; lyr < NLAYER; ++lyr) {
        const long dd = (long)lyr * D_EMB * D_EMB;
        const long d1 = (long)lyr * D_EMB * HMLP;
        wconv_kernel<<<2816, 256, 0, stream>>>(
            Wq + dd, Wk + dd, Wv + dd, W1 + d1, W2 + d1,
            WqT, WkT, WvT, W1T, W2T);
        ln_kernel<<<4096, 256, 0, stream>>>(H, ln1g + lyr * D_EMB, ln1b + lyr * D_EMB, LNb);
        // QKV fused over N=3072 (WqT..WvT contiguous); z==2 cols -> V^T
        gemm8<7><<<dim3(24, 16, 1), 512, 0, stream>>>(
            LNb, WqT, Qb, Kb, VT, nullptr, 3072, D_EMB, D_EMB);
        // scores = Q @ K^T per batch
        gemm_bt<0, 64><<<dim3(16, 8, 4), 256, 0, stream>>>(
            Qb, Kb, S, nullptr, T_TOK, T_TOK, D_EMB, TD, TD, TT, 1.f);
        softmax_kernel<<<4096, 256, 0, stream>>>(S, Pb);
        // H += (1 + 1/D) * P @ V
        gemm_bt<3, 64><<<dim3(16, 8, 4), 256, 0, stream>>>(
            Pb, VT, H, nullptr, T_TOK, D_EMB, T_TOK, TT, TD, TD,
            1.0f + 1.0f / (float)D_EMB);
        ln_kernel<<<4096, 256, 0, stream>>>(H, ln2g + lyr * D_EMB, ln2b + lyr * D_EMB, LNb);
        // hidden = gelu(LN @ W1 + b1) -> bf16
        gemm8<1><<<dim3(32, 16, 1), 512, 0, stream>>>(
            LNb, W1T, Hid, nullptr, nullptr, b1 + (long)lyr * HMLP,
            HMLP, D_EMB, D_EMB);
        // H += hidden @ W2 + b2 (split-K x2, atomic)
        gemm8<6><<<dim3(8, 16, 2), 512, 0, stream>>>(
            Hid, W2T, H, nullptr, nullptr, b2 + (long)lyr * D_EMB,
            D_EMB, HMLP, HMLP / 2);
    }
    // readout: out = (H @ ro_W + ro_b)[:, T2:, :]
    cvt_bf16_kernel<<<4096, 256, 0, stream>>>(H, Hbf);
    convT_kernel<<<dim3(16, 32), 256, 0, stream>>>(roW, roWT, D_EMB, VCLS);
    gemm_bt<4, 64><<<dim3(8, 24, 1), 256, 0, stream>>>(
        Hbf, roWT, out, rob, 4096, VCLS, D_EMB, 0L, 0L, 0L, 1.f);
}

// Round 7
// 3050.842 us; speedup vs baseline: 1.0482x; 1.0005x over previous
//
#include <hip/hip_runtime.h>
#include <hip/hip_bf16.h>
#include <math.h>

#define D_EMB  1024
#define T_TOK  1024
#define T1_TOK 768
#define T2_TOK 256
#define HMLP   4096
#define NLAYER 12
#define VCLS   512

typedef __attribute__((ext_vector_type(8))) short          short8; // 8 bf16
typedef __attribute__((ext_vector_type(4))) float          f32x4;
typedef __attribute__((ext_vector_type(4))) unsigned short us4;
typedef unsigned short us;

__device__ __forceinline__ us f2bf(float f) {
    union { float f; unsigned int u; } c; c.f = f;
    unsigned int u = c.u;
    return (us)((u + 0x7FFFu + ((u >> 16) & 1u)) >> 16); // RNE
}

__device__ __forceinline__ void gld_lds16(const us* g, us* l) {
    __builtin_amdgcn_global_load_lds(
        (__attribute__((address_space(1))) void*)g,
        (__attribute__((address_space(3))) void*)l, 16, 0, 0);
}

// ---------------------------------------------------------------------------
__global__ __launch_bounds__(256)
void embed_kernel(const int* __restrict__ xt, const int* __restrict__ zi,
                  const float* __restrict__ pos, const float* __restrict__ temb,
                  const float* __restrict__ iemb, float* __restrict__ H)
{
    const long idx = (long)blockIdx.x * 256 + threadIdx.x;
    const long e   = idx * 4;
    const int  dd  = (int)(e & (D_EMB - 1));
    const long bt  = e >> 10;
    const int  t   = (int)(bt & (T_TOK - 1));
    const int  b   = (int)(bt >> 10);
    const float* src;
    if (t < T2_TOK) src = iemb + (long)zi[b * T2_TOK + t] * D_EMB + dd;
    else            src = temb + (long)xt[b * T1_TOK + (t - T2_TOK)] * D_EMB + dd;
    float4 sv = *(const float4*)src;
    float4 pv = *(const float4*)(pos + (long)t * D_EMB + dd);
    float4 o; o.x = sv.x + pv.x; o.y = sv.y + pv.y; o.z = sv.z + pv.z; o.w = sv.w + pv.w;
    *(float4*)(H + e) = o;
}

// ---------------------------------------------------------------------------
__global__ __launch_bounds__(256)
void ln_kernel(const float* __restrict__ X, const float* __restrict__ g,
               const float* __restrict__ b, us* __restrict__ Y)
{
    const long row = blockIdx.x;
    const int  tid = threadIdx.x;
    float4 v = *(const float4*)(X + row * D_EMB + tid * 4);
    float s = v.x + v.y + v.z + v.w;
    float q = v.x*v.x + v.y*v.y + v.z*v.z + v.w*v.w;
    #pragma unroll
    for (int o = 32; o >= 1; o >>= 1) { s += __shfl_down(s, o); q += __shfl_down(q, o); }
    __shared__ float rs[4], rq[4];
    const int w = tid >> 6;
    if ((tid & 63) == 0) { rs[w] = s; rq[w] = q; }
    __syncthreads();
    s = rs[0] + rs[1] + rs[2] + rs[3];
    q = rq[0] + rq[1] + rq[2] + rq[3];
    const float mean = s * (1.0f / D_EMB);
    const float var  = q * (1.0f / D_EMB) - mean * mean;
    const float rstd = rsqrtf(var + 1e-5f);
    float4 gg = *(const float4*)(g + tid * 4);
    float4 bb = *(const float4*)(b + tid * 4);
    us4 o;
    o.x = f2bf((v.x - mean) * rstd * gg.x + bb.x);
    o.y = f2bf((v.y - mean) * rstd * gg.y + bb.y);
    o.z = f2bf((v.z - mean) * rstd * gg.z + bb.z);
    o.w = f2bf((v.w - mean) * rstd * gg.w + bb.w);
    *(us4*)(Y + row * D_EMB + tid * 4) = o;
}

// ---------------------------------------------------------------------------
__global__ __launch_bounds__(256)
void softmax_kernel(const float* __restrict__ S, us* __restrict__ P)
{
    const long row = blockIdx.x;
    const int  tid = threadIdx.x;
    float4 v = *(const float4*)(S + row * T_TOK + tid * 4);
    const float sc = 0.03125f; // 1/sqrt(1024)
    float a = v.x * sc, b = v.y * sc, c = v.z * sc, d = v.w * sc;
    float mx = fmaxf(fmaxf(a, b), fmaxf(c, d));
    #pragma unroll
    for (int o = 32; o >= 1; o >>= 1) mx = fmaxf(mx, __shfl_down(mx, o));
    __shared__ float rm[4], rsum[4];
    const int w = tid >> 6;
    if ((tid & 63) == 0) rm[w] = mx;
    __syncthreads();
    mx = fmaxf(fmaxf(rm[0], rm[1]), fmaxf(rm[2], rm[3]));
    float e0 = expf(a - mx), e1 = expf(b - mx), e2 = expf(c - mx), e3 = expf(d - mx);
    float s = e0 + e1 + e2 + e3;
    #pragma unroll
    for (int o = 32; o >= 1; o >>= 1) s += __shfl_down(s, o);
    if ((tid & 63) == 0) rsum[w] = s;
    __syncthreads();
    s = rsum[0] + rsum[1] + rsum[2] + rsum[3];
    const float inv = 1.0f / s;
    us4 o4; o4.x = f2bf(e0 * inv); o4.y = f2bf(e1 * inv);
    o4.z = f2bf(e2 * inv); o4.w = f2bf(e3 * inv);
    *(us4*)(P + row * T_TOK + tid * 4) = o4;
}

// ---------------------------------------------------------------------------
__global__ __launch_bounds__(256)
void convT_kernel(const float* __restrict__ src, us* __restrict__ dst,
                  int K, int N)
{
    __shared__ us tile[32][33];
    const int tn = blockIdx.x, tk = blockIdx.y;
    const int tx = threadIdx.x & 31, ty = threadIdx.x >> 5;
    #pragma unroll
    for (int i = 0; i < 4; ++i) {
        const int r = ty + i * 8;
        tile[r][tx] = f2bf(src[(long)(tk * 32 + r) * N + tn * 32 + tx]);
    }
    __syncthreads();
    #pragma unroll
    for (int i = 0; i < 4; ++i) {
        const int r = ty + i * 8;
        dst[(long)(tn * 32 + r) * K + tk * 32 + tx] = tile[tx][r];
    }
}

// fp32 [K][N] -> bf16 [N][K], 64x64 tiles (float4 in / us4 out)
__global__ __launch_bounds__(256)
void wconv_kernel(const float* __restrict__ Wq, const float* __restrict__ Wk,
                  const float* __restrict__ Wv, const float* __restrict__ W1,
                  const float* __restrict__ W2,
                  us* __restrict__ WqT, us* __restrict__ WkT,
                  us* __restrict__ WvT, us* __restrict__ W1T,
                  us* __restrict__ W2T)
{
    __shared__ us tile[64][66];
    const int t = blockIdx.x;
    const float* src; us* dst; int K, N, tk, tn;
    if (t < 768) {
        const int wsel = t >> 8, tt = t & 255;
        src = (wsel == 0) ? Wq : (wsel == 1) ? Wk : Wv;
        dst = (wsel == 0) ? WqT : (wsel == 1) ? WkT : WvT;
        K = 1024; N = 1024; tk = tt >> 4; tn = tt & 15;
    } else if (t < 1792) {
        const int tt = t - 768;
        src = W1; dst = W1T; K = 1024; N = 4096; tk = tt >> 6; tn = tt & 63;
    } else {
        const int tt = t - 1792;
        src = W2; dst = W2T; K = 4096; N = 1024; tk = tt >> 4; tn = tt & 15;
    }
    const int r  = threadIdx.x >> 4;
    const int c4 = threadIdx.x & 15;
    #pragma unroll
    for (int i = 0; i < 4; ++i) {
        const int row = r + i * 16;
        float4 v = *(const float4*)(src + (long)(tk * 64 + row) * N + tn * 64 + c4 * 4);
        tile[row][c4 * 4 + 0] = f2bf(v.x);
        tile[row][c4 * 4 + 1] = f2bf(v.y);
        tile[row][c4 * 4 + 2] = f2bf(v.z);
        tile[row][c4 * 4 + 3] = f2bf(v.w);
    }
    __syncthreads();
    #pragma unroll
    for (int i = 0; i < 4; ++i) {
        const int rr = r + i * 16;
        us4 o;
        o.x = tile[c4 * 4 + 0][rr];
        o.y = tile[c4 * 4 + 1][rr];
        o.z = tile[c4 * 4 + 2][rr];
        o.w = tile[c4 * 4 + 3][rr];
        *(us4*)(dst + (long)(tn * 64 + rr) * K + tk * 64 + c4 * 4) = o;
    }
}

__global__ __launch_bounds__(256)
void cvt_bf16_kernel(const float* __restrict__ X, us* __restrict__ Y)
{
    const long i = ((long)blockIdx.x * 256 + threadIdx.x) * 4;
    float4 v = *(const float4*)(X + i);
    us4 o; o.x = f2bf(v.x); o.y = f2bf(v.y); o.z = f2bf(v.z); o.w = f2bf(v.w);
    *(us4*)(Y + i) = o;
}

// ===========================================================================
// gemm8: 256xTN tile (TN in {64,128}), BK=64, 8 waves (4Mx2N), 512 thr,
// triple-buffered LDS (TN=128: 144 KB, TN=64: 120 KB), 2 phases/K-tile with
// counted vmcnt (never drained in steady state) + setprio around MFMA.
// Swizzle: LDS slot' = slot ^ (row&7); linear gld_lds dest + pre-swizzled
// global source + swizzled ds_read (rule #21).
// Batched B via sBz: Bp = B + (m0>>10)*sBz (m-tiles never cross batch).
// EPI: 0 fp32 store (QK; N==1024 makes gm*N+gn batch-correct)
//      1 bias+gelu->bf16 (MLP1) | 2 C+=v+bias fp32 RMW (MLP2)
//      3 C+=alpha*v fp32 RMW (PV) | 7 QKV fused N=3072 (2 -> V^T)
// ===========================================================================
template<int EPI, int TN>
__global__ __launch_bounds__(512, 2)
void gemm8(const us* __restrict__ A, const us* __restrict__ B,
           void* __restrict__ C0, void* __restrict__ C1, void* __restrict__ C2,
           const float* __restrict__ bias,
           int N, int K, long sBz, float alpha)
{
    constexpr int FN   = TN / 32;        // B frags per wave (4 or 2)
    constexpr int ABUF = 256 * 64;       // us per A buffer (32 KB)
    constexpr int BBUF = TN * 64;        // us per B buffer (16/8 KB)
    constexpr int BROW = (TN == 128) ? 16 : 8;  // B rows staged per wave
    __shared__ us As[3 * ABUF];
    __shared__ us Bs[3 * BBUF];

    // XCD swizzle (bijective: nwg % 8 == 0 for all launches), n-major decode
    const int gx = gridDim.x, gy = gridDim.y;
    const int o  = blockIdx.x + gx * blockIdx.y;
    const int nwg = gx * gy;
    const int virt = (nwg & 7) ? o : ((o & 7) * (nwg >> 3) + (o >> 3));
    const int ntile = virt / gy;
    const int mtile = virt - ntile * gy;
    const int m0 = mtile * 256, n0 = ntile * TN;

    const us* Bp = B + (long)(m0 >> 10) * sBz;

    const int tid  = threadIdx.x;
    const int lane = tid & 63, w = tid >> 6;          // 8 waves
    const int srow = lane >> 3, sslot = (lane & 7) ^ srow;
    const int lr = lane & 15, hi = lane >> 4;
    const int wm = (w >> 1) * 64, wn = (w & 1) * (TN / 2);

    // staging bases: wave w stages A rows [w*32,+32), B rows [w*BROW,+BROW)
    const us* gA = A + (long)(m0 + w * 32 + srow) * K + sslot * 8;
    const us* gB = Bp + (long)(n0 + w * BROW + srow) * K + sslot * 8;

    f32x4 acc[4][FN];
    #pragma unroll
    for (int f = 0; f < 4; ++f)
        #pragma unroll
        for (int g = 0; g < FN; ++g)
            acc[f][g] = (f32x4){0.f, 0.f, 0.f, 0.f};

    const int nk = K >> 6;  // K-tiles of 64 (>= 16 for all our launches)

    // prologue: stage tiles 0,1 fully; wait tile 0 (tile 1's stay in flight)
    #pragma unroll
    for (int tb = 0; tb < 2; ++tb) {
        #pragma unroll
        for (int j = 0; j < 4; ++j)
            gld_lds16(gA + (long)(j * 8) * K + tb * 64,
                      As + tb * ABUF + (w * 32 + j * 8) * 64);
        if constexpr (TN == 128) {
            #pragma unroll
            for (int j = 0; j < 2; ++j)
                gld_lds16(gB + (long)(j * 8) * K + tb * 64,
                          Bs + tb * BBUF + (w * 16 + j * 8) * 64);
        } else {
            gld_lds16(gB + tb * 64, Bs + tb * BBUF + (w * 8) * 64);
        }
    }
    if constexpr (TN == 128) asm volatile("s_waitcnt vmcnt(6)" ::: "memory");
    else                     asm volatile("s_waitcnt vmcnt(5)" ::: "memory");
    __builtin_amdgcn_s_barrier();

    for (int t = 0; t < nk; ++t) {
        const int cur = t % 3, nb = (t + 2) % 3;
        const us* Ac = As + cur * ABUF;
        const us* Bc = Bs + cur * BBUF;
        const int kk2 = (t + 2) << 6;
        #pragma unroll
        for (int kk = 0; kk < 2; ++kk) {
            short8 af[4], bg[FN];
            #pragma unroll
            for (int f = 0; f < 4; ++f) {
                const int rr = wm + f * 16 + lr;
                af[f] = *(const short8*)&Ac[rr * 64 + (((kk * 4 + hi) ^ (rr & 7)) * 8)];
            }
            #pragma unroll
            for (int g = 0; g < FN; ++g) {
                const int rn = wn + g * 16 + lr;
                bg[g] = *(const short8*)&Bc[rn * 64 + (((kk * 4 + hi) ^ (rn & 7)) * 8)];
            }
            if (t + 2 < nk) {  // stage half kk of tile t+2
                gld_lds16(gA + (long)((kk * 2 + 0) * 8) * K + kk2,
                          As + nb * ABUF + (w * 32 + (kk * 2 + 0) * 8) * 64);
                gld_lds16(gA + (long)((kk * 2 + 1) * 8) * K + kk2,
                          As + nb * ABUF + (w * 32 + (kk * 2 + 1) * 8) * 64);
                if constexpr (TN == 128) {
                    gld_lds16(gB + (long)(kk * 8) * K + kk2,
                              Bs + nb * BBUF + (w * 16 + kk * 8) * 64);
                } else if (kk == 0) {
                    gld_lds16(gB + kk2, Bs + nb * BBUF + (w * 8) * 64);
                }
            }
            __builtin_amdgcn_s_barrier();
            asm volatile("s_waitcnt lgkmcnt(0)" ::: "memory");
            __builtin_amdgcn_sched_barrier(0);
            __builtin_amdgcn_s_setprio(1);
            #pragma unroll
            for (int f = 0; f < 4; ++f)
                #pragma unroll
                for (int g = 0; g < FN; ++g)
                    acc[f][g] = __builtin_amdgcn_mfma_f32_16x16x32_bf16(
                        af[f], bg[g], acc[f][g], 0, 0, 0);
            __builtin_amdgcn_s_setprio(0);
            __builtin_amdgcn_sched_barrier(0);
            if (kk == 1) {
                if (t + 2 < nk) {
                    if constexpr (TN == 128)
                        asm volatile("s_waitcnt vmcnt(6)" ::: "memory");
                    else
                        asm volatile("s_waitcnt vmcnt(5)" ::: "memory");
                } else if (t + 1 < nk) {
                    asm volatile("s_waitcnt vmcnt(0)" ::: "memory");
                }
            }
            __builtin_amdgcn_s_barrier();
        }
    }

    // epilogue. D: col = lane&15 (n), row = hi*4 + r (m)
    #pragma unroll
    for (int f = 0; f < 4; ++f) {
        #pragma unroll
        for (int g = 0; g < FN; ++g) {
            const int gm0 = m0 + wm + f * 16 + hi * 4;
            const int gn  = n0 + wn + g * 16 + lr;
            if constexpr (EPI == 7) {
                const int target = gn >> 10, col = gn & 1023;
                if (target == 2) {  // V^T: VT[b][d][t], 4 consecutive t
                    us4 ov;
                    ov.x = f2bf(acc[f][g][0]); ov.y = f2bf(acc[f][g][1]);
                    ov.z = f2bf(acc[f][g][2]); ov.w = f2bf(acc[f][g][3]);
                    *(us4*)&((us*)C2)[(long)(gm0 >> 10) * (T_TOK * D_EMB)
                                      + (long)col * T_TOK + (gm0 & (T_TOK - 1))] = ov;
                } else {
                    us* dst = target ? (us*)C1 : (us*)C0;
                    #pragma unroll
                    for (int r = 0; r < 4; ++r)
                        dst[(long)(gm0 + r) * D_EMB + col] = f2bf(acc[f][g][r]);
                }
            } else if constexpr (EPI == 1) {
                #pragma unroll
                for (int r = 0; r < 4; ++r) {
                    float v = acc[f][g][r] + bias[gn];
                    const float ge = 0.5f * v * (1.0f + erff(v * 0.70710678118f));
                    ((us*)C0)[(long)(gm0 + r) * N + gn] = f2bf(ge);
                }
            } else if constexpr (EPI == 0) {
                #pragma unroll
                for (int r = 0; r < 4; ++r)
                    ((float*)C0)[(long)(gm0 + r) * N + gn] = acc[f][g][r];
            } else if constexpr (EPI == 2) {
                #pragma unroll
                for (int r = 0; r < 4; ++r) {
                    float* c = (float*)C0 + (long)(gm0 + r) * N + gn;
                    *c = *c + acc[f][g][r] + bias[gn];
                }
            } else { // EPI == 3
                #pragma unroll
                for (int r = 0; r < 4; ++r) {
                    float* c = (float*)C0 + (long)(gm0 + r) * N + gn;
                    *c = *c + alpha * acc[f][g][r];
                }
            }
        }
    }
}

// ---------------------------------------------------------------------------
// 2-buffer 128x64 GEMM, used only for the readout slice (EPI 4).
// ---------------------------------------------------------------------------
template<int EPI, int TN>
__global__ __launch_bounds__(256)
void gemm_bt(const us* __restrict__ A, const us* __restrict__ B0,
             void* __restrict__ C0, const float* __restrict__ bias,
             int M, int N, int K,
             long sAz, long sBz, long sCz, float alpha)
{
    constexpr int FN = TN / 32;
    constexpr int ABUF = 128 * 32;
    constexpr int BBUF = TN * 32;
    __shared__ us As[2 * ABUF];
    __shared__ us Bs[2 * BBUF];

    const us* Ap = A;
    const us* Bp = B0;

    const int gx = gridDim.x, gy = gridDim.y;
    const int o  = blockIdx.x + gx * blockIdx.y;
    const int nwg = gx * gy;
    const int virt = (nwg & 7) ? o : ((o & 7) * (nwg >> 3) + (o >> 3));
    const int ntile = virt / gy;
    int mtile = virt - ntile * gy;
    if constexpr (EPI == 4) mtile = (mtile / 6) * 8 + 2 + (mtile % 6);
    const int m0 = mtile * 128, n0 = ntile * TN;

    const int tid = threadIdx.x;
    const int l = tid & 63, w = tid >> 6;
    const int wm = (w >> 1) * 64, wn = (w & 1) * (TN / 2);
    const int lr = l & 15, hi = l >> 4;

    const int r0 = tid >> 2;
    const int s0 = (tid & 3) ^ ((r0 >> 1) & 3);
    const us* gA0 = Ap + (long)(m0 + r0) * K + s0 * 8;
    const us* gA1 = Ap + (long)(m0 + r0 + 64) * K + s0 * 8;
    const us* gB0 = Bp + (long)(n0 + r0) * K + s0 * 8;
    const int lA0 = w * 512, lA1 = 2048 + w * 512;
    const int lB0 = w * 512;

    f32x4 acc[4][FN];
    #pragma unroll
    for (int f = 0; f < 4; ++f)
        #pragma unroll
        for (int gq = 0; gq < FN; ++gq)
            acc[f][gq] = (f32x4){0.f, 0.f, 0.f, 0.f};

    const int nk = K >> 5;
    gld_lds16(gA0, As + lA0);
    gld_lds16(gA1, As + lA1);
    gld_lds16(gB0, Bs + lB0);
    __syncthreads();

    for (int t = 0; t < nk; ++t) {
        const int cur = t & 1;
        const int aB = (cur ^ 1) * ABUF, bB = (cur ^ 1) * BBUF;
        if (t + 1 < nk) {
            const int k1 = (t + 1) << 5;
            gld_lds16(gA0 + k1, As + aB + lA0);
            gld_lds16(gA1 + k1, As + aB + lA1);
            gld_lds16(gB0 + k1, Bs + bB + lB0);
        }
        const int aC = cur * ABUF, bC = cur * BBUF;
        short8 af[4], bg[FN];
        #pragma unroll
        for (int f = 0; f < 4; ++f) {
            const int rr = wm + f * 16 + lr;
            const int sl = hi ^ ((rr >> 1) & 3);
            af[f] = *(const short8*)&As[aC + rr * 32 + sl * 8];
        }
        #pragma unroll
        for (int gq = 0; gq < FN; ++gq) {
            const int rn = wn + gq * 16 + lr;
            const int sl = hi ^ ((rn >> 1) & 3);
            bg[gq] = *(const short8*)&Bs[bC + rn * 32 + sl * 8];
        }
        #pragma unroll
        for (int f = 0; f < 4; ++f)
            #pragma unroll
            for (int gq = 0; gq < FN; ++gq)
                acc[f][gq] = __builtin_amdgcn_mfma_f32_16x16x32_bf16(
                    af[f], bg[gq], acc[f][gq], 0, 0, 0);
        __syncthreads();
    }

    #pragma unroll
    for (int f = 0; f < 4; ++f) {
        #pragma unroll
        for (int gq = 0; gq < FN; ++gq) {
            #pragma unroll
            for (int r = 0; r < 4; ++r) {
                const int gm = m0 + wm + f * 16 + hi * 4 + r;
                const int gn = n0 + wn + gq * 16 + lr;
                const int tt = gm & (T_TOK - 1);
                ((float*)C0)[(long)((gm >> 10) * T1_TOK + (tt - T2_TOK)) * VCLS + gn]
                    = acc[f][gq][r] + bias[gn];
            }
        }
    }
}

// ---------------------------------------------------------------------------
extern "C" void kernel_launch(void* const* d_in, const int* in_sizes, int n_in,
                              void* d_out, int out_size, void* d_ws, size_t ws_size,
                              hipStream_t stream)
{
    (void)in_sizes; (void)n_in; (void)out_size; (void)ws_size;
    const int*   xt   = (const int*)d_in[0];
    const int*   zi   = (const int*)d_in[1];
    const float* pos  = (const float*)d_in[2];
    const float* temb = (const float*)d_in[3];
    const float* iemb = (const float*)d_in[4];
    const float* ln1g = (const float*)d_in[5];
    const float* ln1b = (const float*)d_in[6];
    const float* Wq   = (const float*)d_in[7];
    const float* Wk   = (const float*)d_in[8];
    const float* Wv   = (const float*)d_in[9];
    const float* ln2g = (const float*)d_in[10];
    const float* ln2b = (const float*)d_in[11];
    const float* W1   = (const float*)d_in[12];
    const float* b1   = (const float*)d_in[13];
    const float* W2   = (const float*)d_in[14];
    const float* b2   = (const float*)d_in[15];
    const float* roW  = (const float*)d_in[16];
    const float* rob  = (const float*)d_in[17];
    float* out = (float*)d_out;

    char* wsb = (char*)d_ws;
    float* H    = (float*)(wsb + 0);                 // 16 MB fp32
    us*    LNb  = (us*)(wsb + 16777216);             // 8 MB bf16
    float* S    = (float*)(wsb + 25165824);          // 16 MB fp32
    us*    Qb   = (us*)(wsb + 41943040);             // 8 MB
    us*    Kb   = (us*)(wsb + 50331648);             // 8 MB
    us*    VT   = (us*)(wsb + 58720256);             // 8 MB (V^T per batch)
    us*    Pb   = (us*)(wsb + 67108864);             // 8 MB
    us*    Hid  = (us*)(wsb + 41943040);             // 32 MB, overlaps Q..P
    us*    WqT  = (us*)(wsb + 75497472);             // 2 MB (Wq,Wk,Wv contiguous)
    us*    WkT  = (us*)(wsb + 77594624);
    us*    WvT  = (us*)(wsb + 79691776);
    us*    W1T  = (us*)(wsb + 81788928);             // 8 MB
    us*    W2T  = (us*)(wsb + 90177536);             // 8 MB
    us*    roWT = W1T;
    us*    Hbf  = LNb;

    const long TD = (long)T_TOK * D_EMB;

    embed_kernel<<<4096, 256, 0, stream>>>(xt, zi, pos, temb, iemb, H);

    for (int lyr = 0; lyr < NLAYER; ++lyr) {
        const long dd = (long)lyr * D_EMB * D_EMB;
        const long d1 = (long)lyr * D_EMB * HMLP;
        wconv_kernel<<<2816, 256, 0, stream>>>(
            Wq + dd, Wk + dd, Wv + dd, W1 + d1, W2 + d1,
            WqT, WkT, WvT, W1T, W2T);
        ln_kernel<<<4096, 256, 0, stream>>>(H, ln1g + lyr * D_EMB, ln1b + lyr * D_EMB, LNb);
        // QKV fused over N=3072 (WqT..WvT contiguous); cols>=2048 -> V^T
        gemm8<7, 64><<<dim3(48, 16, 1), 512, 0, stream>>>(
            LNb, WqT, Qb, Kb, VT, nullptr, 3072, D_EMB, 0L, 1.f);
        // scores = Q @ K^T per batch (B batched via sBz)
        gemm8<0, 64><<<dim3(16, 16, 1), 512, 0, stream>>>(
            Qb, Kb, S, nullptr, nullptr, nullptr, T_TOK, D_EMB, TD, 1.f);
        softmax_kernel<<<4096, 256, 0, stream>>>(S, Pb);
        // H += (1 + 1/D) * P @ V  (B batched via sBz)
        gemm8<3, 64><<<dim3(16, 16, 1), 512, 0, stream>>>(
            Pb, VT, H, nullptr, nullptr, nullptr, D_EMB, T_TOK, TD,
            1.0f + 1.0f / (float)D_EMB);
        ln_kernel<<<4096, 256, 0, stream>>>(H, ln2g + lyr * D_EMB, ln2b + lyr * D_EMB, LNb);
        // hidden = gelu(LN @ W1 + b1) -> bf16
        gemm8<1, 128><<<dim3(32, 16, 1), 512, 0, stream>>>(
            LNb, W1T, Hid, nullptr, nullptr, b1 + (long)lyr * HMLP,
            HMLP, D_EMB, 0L, 1.f);
        // H += hidden @ W2 + b2  (no split-K, plain fp32 RMW)
        gemm8<2, 64><<<dim3(16, 16, 1), 512, 0, stream>>>(
            Hid, W2T, H, nullptr, nullptr, b2 + (long)lyr * D_EMB,
            D_EMB, HMLP, 0L, 1.f);
    }
    // readout: out = (H @ ro_W + ro_b)[:, T2:, :]
    cvt_bf16_kernel<<<4096, 256, 0, stream>>>(H, Hbf);
    convT_kernel<<<dim3(16, 32), 256, 0, stream>>>(roW, roWT, D_EMB, VCLS);
    gemm_bt<4, 64><<<dim3(8, 24, 1), 256, 0, stream>>>(
        Hbf, roWT, out, rob, 4096, VCLS, D_EMB, 0L, 0L, 0L, 1.f);
}